// Round 12
// baseline (211.677 us; speedup 1.0000x reference)
//
#include <hip/hip_runtime.h>
#include <hip/hip_bf16.h>
#include <math.h>

typedef unsigned short u16;
typedef __bf16 bf16x8 __attribute__((ext_vector_type(8)));
typedef float f32x4 __attribute__((ext_vector_type(4)));
typedef unsigned short u16x8 __attribute__((ext_vector_type(8)));

typedef const __attribute__((address_space(1))) void* gas_ptr;
typedef __attribute__((address_space(3))) void* las_ptr;

__device__ __forceinline__ float bf2f(u16 u) {
    union { unsigned int i; float f; } x;
    x.i = ((unsigned int)u) << 16;
    return x.f;
}
__device__ __forceinline__ u16 f2bf(float f) {
    __hip_bfloat16 h = __float2bfloat16(f);
    return __builtin_bit_cast(u16, h);
}
__device__ __forceinline__ __bf16 f2bfr(float f) {
    __hip_bfloat16 h = __float2bfloat16(f);
    return __builtin_bit_cast(__bf16, h);
}
__device__ __forceinline__ void load_lds16(const void* g, void* l) {
    __builtin_amdgcn_global_load_lds((gas_ptr)g, (las_ptr)l, 16, 0, 0);
}
// GELU with exact-erf semantics via A&S 7.1.26 (|err_erf| <= 1.5e-7).
__device__ __forceinline__ float gelu_f(float v) {
    const float a = fabsf(v) * 0.70710678118654752f;
    const float tt = 1.0f / fmaf(0.3275911f, a, 1.0f);
    float poly = fmaf(tt, 1.061405429f, -1.453152027f);
    poly = fmaf(tt, poly, 1.421413741f);
    poly = fmaf(tt, poly, -0.284496736f);
    poly = fmaf(tt, poly, 0.254829592f);
    const float erfa = 1.0f - poly * tt * __expf(-a * a);
    const float erfv = copysignf(erfa, v);
    return 0.5f * v * (1.0f + erfv);
}

// ---------------------------------------------------------------------------
// All 4 weight conversions f32->bf16 in one launch. 1024 elems/block.
// ---------------------------------------------------------------------------
__global__ __launch_bounds__(256) void cvt_all_k(const float* __restrict__ qkv_w,
                                                 const float* __restrict__ proj_w,
                                                 const float* __restrict__ fc1w,
                                                 const float* __restrict__ fc2w,
                                                 u16* __restrict__ wqkv,
                                                 u16* __restrict__ wproj,
                                                 u16* __restrict__ wfc1,
                                                 u16* __restrict__ wfc2) {
    const int b = blockIdx.x;
    const float* src; u16* dst; int off;
    if (b < 768)       { src = qkv_w;  dst = wqkv;  off = b; }
    else if (b < 1024) { src = proj_w; dst = wproj; off = b - 768; }
    else if (b < 2048) { src = fc1w;   dst = wfc1;  off = b - 1024; }
    else               { src = fc2w;   dst = wfc2;  off = b - 2048; }
    const int i = off * 256 + threadIdx.x;
    const float4 v = ((const float4*)src)[i];
    ushort4 o;
    o.x = f2bf(v.x); o.y = f2bf(v.y); o.z = f2bf(v.z); o.w = f2bf(v.w);
    ((ushort4*)dst)[i] = o;
}

// ---------------------------------------------------------------------------
// LN1: one WAVE per row (C=512), 4 rows/block, no LDS/barrier. f32 -> bf16.
// ---------------------------------------------------------------------------
__global__ __launch_bounds__(256) void ln_row_k(const float* __restrict__ x,
                                                const float* __restrict__ gw,
                                                const float* __restrict__ gb,
                                                u16* __restrict__ outp) {
    const int row = blockIdx.x * 4 + (threadIdx.x >> 6);
    const int lane = threadIdx.x & 63;
    const float* rp = x + (size_t)row * 512 + lane * 8;
    const float4 a = *(const float4*)rp;
    const float4 b = *(const float4*)(rp + 4);
    float s = a.x + a.y + a.z + a.w + b.x + b.y + b.z + b.w;
    float q = a.x*a.x + a.y*a.y + a.z*a.z + a.w*a.w
            + b.x*b.x + b.y*b.y + b.z*b.z + b.w*b.w;
    #pragma unroll
    for (int o = 1; o < 64; o <<= 1) {
        s += __shfl_xor(s, o);
        q += __shfl_xor(q, o);
    }
    const float mean = s * (1.0f / 512.0f);
    const float var = q * (1.0f / 512.0f) - mean * mean;
    const float rstd = rsqrtf(var + 1e-5f);
    const float4 g0 = *(const float4*)(gw + lane * 8);
    const float4 g1 = *(const float4*)(gw + lane * 8 + 4);
    const float4 c0 = *(const float4*)(gb + lane * 8);
    const float4 c1 = *(const float4*)(gb + lane * 8 + 4);
    u16x8 o16;
    o16[0] = f2bf((a.x - mean) * rstd * g0.x + c0.x);
    o16[1] = f2bf((a.y - mean) * rstd * g0.y + c0.y);
    o16[2] = f2bf((a.z - mean) * rstd * g0.z + c0.z);
    o16[3] = f2bf((a.w - mean) * rstd * g0.w + c0.w);
    o16[4] = f2bf((b.x - mean) * rstd * g1.x + c1.x);
    o16[5] = f2bf((b.y - mean) * rstd * g1.y + c1.y);
    o16[6] = f2bf((b.z - mean) * rstd * g1.z + c1.z);
    o16[7] = f2bf((b.w - mean) * rstd * g1.w + c1.w);
    *(u16x8*)(outp + (size_t)row * 512 + lane * 8) = o16;
}

// ---------------------------------------------------------------------------
// LN2: one WAVE per row, bf16 in -> bf16 out, in-wave stats, no barrier.
// ---------------------------------------------------------------------------
__global__ __launch_bounds__(256) void ln_row_bf_k(const u16* __restrict__ x1,
                                                   const float* __restrict__ gw,
                                                   const float* __restrict__ gb,
                                                   u16* __restrict__ outp) {
    const int row = blockIdx.x * 4 + (threadIdx.x >> 6);
    const int lane = threadIdx.x & 63;
    const u16x8 v = *(const u16x8*)(x1 + (size_t)row * 512 + lane * 8);
    float f[8];
    float s = 0.f, q = 0.f;
    #pragma unroll
    for (int e = 0; e < 8; ++e) {
        f[e] = bf2f(v[e]);
        s += f[e]; q += f[e] * f[e];
    }
    #pragma unroll
    for (int o = 1; o < 64; o <<= 1) {
        s += __shfl_xor(s, o);
        q += __shfl_xor(q, o);
    }
    const float mean = s * (1.0f / 512.0f);
    const float var = q * (1.0f / 512.0f) - mean * mean;
    const float rstd = rsqrtf(var + 1e-5f);
    const float4 g0 = *(const float4*)(gw + lane * 8);
    const float4 g1 = *(const float4*)(gw + lane * 8 + 4);
    const float4 c0 = *(const float4*)(gb + lane * 8);
    const float4 c1 = *(const float4*)(gb + lane * 8 + 4);
    u16x8 o16;
    o16[0] = f2bf((f[0] - mean) * rstd * g0.x + c0.x);
    o16[1] = f2bf((f[1] - mean) * rstd * g0.y + c0.y);
    o16[2] = f2bf((f[2] - mean) * rstd * g0.z + c0.z);
    o16[3] = f2bf((f[3] - mean) * rstd * g0.w + c0.w);
    o16[4] = f2bf((f[4] - mean) * rstd * g1.x + c1.x);
    o16[5] = f2bf((f[5] - mean) * rstd * g1.y + c1.y);
    o16[6] = f2bf((f[6] - mean) * rstd * g1.z + c1.z);
    o16[7] = f2bf((f[7] - mean) * rstd * g1.w + c1.w);
    *(u16x8*)(outp + (size_t)row * 512 + lane * 8) = o16;
}

// ---------------------------------------------------------------------------
// GEMM C[m,n] = sum_k A[m,k]*W[n,k] (+epilogue). 128x128 tile, BK=64,
// 4 waves (2x2), each wave 64x64 via 4x4 mfma 16x16x32 (x2 K-halves).
// r8-proven core: 2-buffer LDS (64 KB), one __syncthreads per K-tile,
// swizzle slot = granule ^ (row&7) both sides (0 conflicts measured),
// A/B loads interleaved per j in stage.
// NEW: LDS-transpose epilogue. After the loop the 64 KB LDS is dead; each
// half (64 tile rows) stages raw acc as f32 in a [64][129] buffer (pad +1:
// reads 2-way = free, writes 4-way = 1.58x), then each thread reads one
// row x 32 contiguous cols, applies bias/residual/gelu with VECTOR loads,
// and stores 4x u16x8 (or 8x float4). Global-store instrs: 64 scalar -> 8.
// AFUSE 1 (proj): A = M*O' + (1-M)*x computed in regs inline (r8 style).
// EPI 0: bf16 = acc (qkv); EPI 1: bf16 = acc+bias+res_f (proj);
// EPI 2: bf16 = gelu(acc+bias) (fc1); EPI 3: f32 = acc+bias+bf16res (fc2).
// ---------------------------------------------------------------------------
template<int EPI, int AFUSE>
__global__ __launch_bounds__(256) void gemm_bt(const u16* __restrict__ A,
                                               const u16* __restrict__ W,
                                               const float* __restrict__ bias,
                                               const float* __restrict__ res_f,
                                               const u16* __restrict__ res_bf,
                                               void* __restrict__ outp,
                                               int M, int N, int K,
                                               const float* __restrict__ aM,
                                               const u16* __restrict__ aO,
                                               const float* __restrict__ aX) {
    __shared__ __align__(16) char smem[65536];
    __bf16* Asm = (__bf16*)smem;             // As[buf][8192] at buf*8192
    __bf16* Bsm = (__bf16*)(smem + 32768);
    float*  EP  = (float*)smem;              // epilogue [64][129] f32

    const int t = threadIdx.x;
    const int l = t & 63;
    const int w = t >> 6;
    const int wm = w & 1, wn = w >> 1;
    const int bm = blockIdx.x * 128, bn = blockIdx.y * 128;
    const int r = l & 15, g4 = l >> 4;

    f32x4 acc[4][4] = {};

    // staging geometry: 1024 granules/tile; thread t handles granules
    // {t, t+256, t+512, t+768} -> rows rowS+32j, within-row slot t&7.
    const int rowS = t >> 3;
    const int cS = (t & 7) ^ (rowS & 7);
    const size_t rstep = (size_t)32 * K;
    const u16* wBase = W + (size_t)(bn + rowS) * K + cS * 8;
    const u16* aBase = A + (size_t)(bm + rowS) * K + cS * 8;
    const size_t afBase = (size_t)(bm + rowS) * K + cS * 8;

    auto stage = [&](int buf, int kt) {
        #pragma unroll
        for (int j = 0; j < 4; ++j) {
            if (AFUSE == 1) {
                const size_t gidx = afBase + j * rstep + kt;
                const float Mw = aM[(bm + rowS + j * 32) >> 6];
                const float rf = 1.0f - Mw;
                const u16x8 ov = *(const u16x8*)(aO + gidx);
                const float4 x0 = *(const float4*)(aX + gidx);
                const float4 x1 = *(const float4*)(aX + gidx + 4);
                bf16x8 val;
                val[0] = f2bfr(Mw * bf2f(ov[0]) + rf * x0.x);
                val[1] = f2bfr(Mw * bf2f(ov[1]) + rf * x0.y);
                val[2] = f2bfr(Mw * bf2f(ov[2]) + rf * x0.z);
                val[3] = f2bfr(Mw * bf2f(ov[3]) + rf * x0.w);
                val[4] = f2bfr(Mw * bf2f(ov[4]) + rf * x1.x);
                val[5] = f2bfr(Mw * bf2f(ov[5]) + rf * x1.y);
                val[6] = f2bfr(Mw * bf2f(ov[6]) + rf * x1.z);
                val[7] = f2bfr(Mw * bf2f(ov[7]) + rf * x1.w);
                *(bf16x8*)&Asm[buf * 8192 + (j * 256 + t) * 8] = val;
            } else {
                load_lds16(aBase + j * rstep + kt,
                           &Asm[buf * 8192 + (j * 256 + t) * 8]);
            }
            load_lds16(wBase + j * rstep + kt,
                       &Bsm[buf * 8192 + (j * 256 + t) * 8]);
        }
    };

    const int nk = K >> 6;
    stage(0, 0);
    __syncthreads();
    for (int s = 0; s < nk; ++s) {
        if (s + 1 < nk) stage((s + 1) & 1, (s + 1) << 6);
        const int buf = s & 1;
        bf16x8 af[4][2], bfr[4][2];
        #pragma unroll
        for (int i = 0; i < 4; ++i) {
            const int ra = wm * 64 + i * 16 + r;
            const int rb = wn * 64 + i * 16 + r;
            #pragma unroll
            for (int h = 0; h < 2; ++h) {
                af[i][h]  = *(const bf16x8*)&Asm[buf * 8192 + ra * 64 + (((h * 4 + g4) ^ (ra & 7)) << 3)];
                bfr[i][h] = *(const bf16x8*)&Bsm[buf * 8192 + rb * 64 + (((h * 4 + g4) ^ (rb & 7)) << 3)];
            }
        }
        #pragma unroll
        for (int i = 0; i < 4; ++i)
            #pragma unroll
            for (int j = 0; j < 4; ++j)
                #pragma unroll
                for (int h = 0; h < 2; ++h)
                    acc[i][j] = __builtin_amdgcn_mfma_f32_16x16x32_bf16(
                        af[i][h], bfr[j][h], acc[i][j], 0, 0, 0);
        __syncthreads();
    }
    // loop's final barrier (with its implicit lgkmcnt(0)) makes LDS reusable.

    // ---- LDS-transpose epilogue ----
    const int erow = t & 63;          // EP row this thread reads back
    const int cb   = (t >> 6) * 32;   // 32-col block
    // per-thread vector operands for the read phase (cols bn+cb .. +31)
    float bias32[32];
    if (EPI != 0) {
        #pragma unroll
        for (int k4 = 0; k4 < 8; ++k4)
            *(float4*)&bias32[k4 * 4] = *(const float4*)(bias + bn + cb + k4 * 4);
    }

    #pragma unroll
    for (int half = 0; half < 2; ++half) {
        // write phase: 32 values (i = half*2 + ii)
        #pragma unroll
        for (int ii = 0; ii < 2; ++ii) {
            const int i = half * 2 + ii;
            #pragma unroll
            for (int j = 0; j < 4; ++j) {
                #pragma unroll
                for (int rr = 0; rr < 4; ++rr) {
                    const int rl = wm * 32 + ii * 16 + g4 * 4 + rr;
                    EP[rl * 129 + wn * 64 + j * 16 + r] = acc[i][j][rr];
                }
            }
        }
        __syncthreads();
        // read + vectorized store phase
        const int m = bm + (erow >> 5) * 64 + (half * 2 + ((erow >> 4) & 1)) * 16 + (erow & 15);
        float vals[32];
        #pragma unroll
        for (int k = 0; k < 32; ++k) vals[k] = EP[erow * 129 + cb + k];
        const size_t obase = (size_t)m * N + bn + cb;
        if (EPI == 0) {
            u16x8 ov[4];
            #pragma unroll
            for (int k = 0; k < 32; ++k) ov[k >> 3][k & 7] = f2bf(vals[k]);
            #pragma unroll
            for (int k8 = 0; k8 < 4; ++k8)
                *(u16x8*)((u16*)outp + obase + k8 * 8) = ov[k8];
        } else if (EPI == 1) {
            float rv[32];
            #pragma unroll
            for (int k4 = 0; k4 < 8; ++k4)
                *(float4*)&rv[k4 * 4] = *(const float4*)(res_f + obase + k4 * 4);
            u16x8 ov[4];
            #pragma unroll
            for (int k = 0; k < 32; ++k)
                ov[k >> 3][k & 7] = f2bf(vals[k] + bias32[k] + rv[k]);
            #pragma unroll
            for (int k8 = 0; k8 < 4; ++k8)
                *(u16x8*)((u16*)outp + obase + k8 * 8) = ov[k8];
        } else if (EPI == 2) {
            u16x8 ov[4];
            #pragma unroll
            for (int k = 0; k < 32; ++k)
                ov[k >> 3][k & 7] = f2bf(gelu_f(vals[k] + bias32[k]));
            #pragma unroll
            for (int k8 = 0; k8 < 4; ++k8)
                *(u16x8*)((u16*)outp + obase + k8 * 8) = ov[k8];
        } else {
            u16x8 rv[4];
            #pragma unroll
            for (int k8 = 0; k8 < 4; ++k8)
                rv[k8] = *(const u16x8*)(res_bf + obase + k8 * 8);
            #pragma unroll
            for (int k4 = 0; k4 < 8; ++k4) {
                float4 o4;
                o4.x = vals[k4 * 4]     + bias32[k4 * 4]     + bf2f(rv[k4 >> 1][(k4 & 1) * 4]);
                o4.y = vals[k4 * 4 + 1] + bias32[k4 * 4 + 1] + bf2f(rv[k4 >> 1][(k4 & 1) * 4 + 1]);
                o4.z = vals[k4 * 4 + 2] + bias32[k4 * 4 + 2] + bf2f(rv[k4 >> 1][(k4 & 1) * 4 + 2]);
                o4.w = vals[k4 * 4 + 3] + bias32[k4 * 4 + 3] + bf2f(rv[k4 >> 1][(k4 & 1) * 4 + 3]);
                *(float4*)((float*)outp + obase + k4 * 4) = o4;
            }
        }
        __syncthreads();
    }
}

// ---------------------------------------------------------------------------
// Fused attention per (window, head): S = QK^T + 0.1*rpe ; Mpart = sum|S| ;
// P' = 1 - cos(S/||S||row * pi/2) ; O' = P' @ V  (M factor applied later).
// ---------------------------------------------------------------------------
__global__ __launch_bounds__(256) void attn_k(const u16* __restrict__ qkv,
                                              const float* __restrict__ rpe,
                                              float* __restrict__ Mpart,
                                              u16* __restrict__ Obuf) {
    const int blk = blockIdx.x;
    const int wh = blk >> 3, head = blk & 7;
    const int himg = wh & 63;
    const int t = threadIdx.x, l = t & 63, w = t >> 6;
    __shared__ __bf16 Qs[4096];
    __shared__ __bf16 Ks[4096];
    __shared__ __bf16 Vt[4096];
    __shared__ __bf16 Ps[4096];
    __shared__ float red[4];

    #pragma unroll
    for (int p = 0; p < 2; ++p) {
        const int sb = (p * 256 + t) << 4;
        const int row = sb >> 7;
        const int gl = ((sb >> 4) & 7) ^ (row & 7);
        const size_t gsrc = (size_t)(wh * 64 + row) * 1536 + head * 64 + gl * 8;
        const int lbase = p * 2048 + w * 512;
        load_lds16(qkv + gsrc, &Qs[lbase]);
        load_lds16(qkv + gsrc + 512, &Ks[lbase]);
    }
    {
        const int k = t >> 2, dc = (t & 3) * 16;
        const u16* vr = qkv + (size_t)(wh * 64 + k) * 1536 + 1024 + head * 64 + dc;
        u16x8 v0 = *(const u16x8*)vr;
        u16x8 v1 = *(const u16x8*)(vr + 8);
        const int g = k >> 3, klo = k & 7;
        #pragma unroll
        for (int i = 0; i < 8; ++i) {
            const int d0 = dc + i, d1 = dc + 8 + i;
            Vt[d0 * 64 + ((g ^ (d0 & 7)) << 3) + klo] = __builtin_bit_cast(__bf16, (u16)v0[i]);
            Vt[d1 * 64 + ((g ^ (d1 & 7)) << 3) + klo] = __builtin_bit_cast(__bf16, (u16)v1[i]);
        }
    }
    __syncthreads();

    const int r = l & 15, g4 = l >> 4;
    f32x4 acc[4] = {};
    #pragma unroll
    for (int h = 0; h < 2; ++h) {
        const int rowq = w * 16 + r;
        bf16x8 aq = *(const bf16x8*)&Qs[rowq * 64 + (((h * 4 + g4) ^ (rowq & 7)) << 3)];
        #pragma unroll
        for (int j = 0; j < 4; ++j) {
            const int rowk = j * 16 + r;
            bf16x8 bk = *(const bf16x8*)&Ks[rowk * 64 + (((h * 4 + g4) ^ (rowk & 7)) << 3)];
            acc[j] = __builtin_amdgcn_mfma_f32_16x16x32_bf16(aq, bk, acc[j], 0, 0, 0);
        }
    }

    float v[4][4];
    float asum = 0.f;
    float ss[4] = {0.f, 0.f, 0.f, 0.f};
    const size_t rpe_base = (size_t)(himg * 8 + head) * 4096 + (size_t)(w * 16 + g4 * 4) * 64 + r;
    #pragma unroll
    for (int j = 0; j < 4; ++j) {
        #pragma unroll
        for (int rr = 0; rr < 4; ++rr) {
            const float val = acc[j][rr] + 0.1f * rpe[rpe_base + rr * 64 + j * 16];
            v[j][rr] = val;
            asum += fabsf(val);
            ss[rr] += val * val;
        }
    }
    #pragma unroll
    for (int m = 1; m < 16; m <<= 1) {
        #pragma unroll
        for (int rr = 0; rr < 4; ++rr) ss[rr] += __shfl_xor(ss[rr], m);
    }
    float srev[4];
    #pragma unroll
    for (int rr = 0; rr < 4; ++rr)
        srev[rr] = 0.25f / fmaxf(sqrtf(ss[rr]), 1e-12f);

    #pragma unroll
    for (int j = 0; j < 4; ++j) {
        #pragma unroll
        for (int rr = 0; rr < 4; ++rr) {
            const float pv = 1.0f - __builtin_amdgcn_cosf(v[j][rr] * srev[rr]);
            const int rl = g4 * 4 + rr;
            const int c = j * 16 + r;
            Ps[w * 1024 + rl * 64 + (((c >> 3) ^ (rl & 7)) << 3) + (c & 7)] = f2bfr(pv);
        }
    }

    f32x4 oacc[4] = {};
    #pragma unroll
    for (int ks = 0; ks < 2; ++ks) {
        const int ga = ks * 4 + g4;
        bf16x8 pa = *(const bf16x8*)&Ps[w * 1024 + r * 64 + ((ga ^ (r & 7)) << 3)];
        #pragma unroll
        for (int j = 0; j < 4; ++j) {
            const int d = j * 16 + r;
            bf16x8 vb = *(const bf16x8*)&Vt[d * 64 + ((ga ^ (d & 7)) << 3)];
            oacc[j] = __builtin_amdgcn_mfma_f32_16x16x32_bf16(pa, vb, oacc[j], 0, 0, 0);
        }
    }

    #pragma unroll
    for (int j = 0; j < 4; ++j) {
        #pragma unroll
        for (int rr = 0; rr < 4; ++rr) {
            const int token = wh * 64 + w * 16 + g4 * 4 + rr;
            Obuf[(size_t)token * 512 + head * 64 + j * 16 + r] = f2bf(oacc[j][rr]);
        }
    }

    #pragma unroll
    for (int o = 1; o < 64; o <<= 1) asum += __shfl_xor(asum, o);
    if (l == 0) red[w] = asum;
    __syncthreads();
    if (t == 0) Mpart[blk] = red[0] + red[1] + red[2] + red[3];
}

// ---------------------------------------------------------------------------
// M finalize: M_w = mean|S| per window; M = max(M_w / max_w, 0.5). 1 block.
// ---------------------------------------------------------------------------
__global__ __launch_bounds__(256) void mfinal_k(const float* __restrict__ Mpart,
                                                float* __restrict__ M) {
    const int t = threadIdx.x;
    float m = 0.f;
    #pragma unroll
    for (int h = 0; h < 8; ++h) m += Mpart[t * 8 + h];
    m *= (1.0f / 32768.0f);
    float mx = m;
    #pragma unroll
    for (int o = 1; o < 64; o <<= 1) mx = fmaxf(mx, __shfl_xor(mx, o));
    __shared__ float red[4];
    if ((t & 63) == 0) red[t >> 6] = mx;
    __syncthreads();
    mx = fmaxf(fmaxf(red[0], red[1]), fmaxf(red[2], red[3]));
    M[t] = fmaxf(m / mx, 0.5f);
}

// ---------------------------------------------------------------------------
extern "C" void kernel_launch(void* const* d_in, const int* in_sizes, int n_in,
                              void* d_out, int out_size, void* d_ws, size_t ws_size,
                              hipStream_t stream) {
    (void)in_sizes; (void)n_in; (void)out_size; (void)ws_size;
    const float* x      = (const float*)d_in[0];
    const float* rpe    = (const float*)d_in[1];
    const float* qkv_w  = (const float*)d_in[2];
    const float* proj_w = (const float*)d_in[3];
    const float* proj_b = (const float*)d_in[4];
    const float* n1w    = (const float*)d_in[5];
    const float* n1b    = (const float*)d_in[6];
    const float* n2w    = (const float*)d_in[7];
    const float* n2b    = (const float*)d_in[8];
    const float* fc1w   = (const float*)d_in[9];
    const float* fc1b   = (const float*)d_in[10];
    const float* fc2w   = (const float*)d_in[11];
    const float* fc2b   = (const float*)d_in[12];
    float* out = (float*)d_out;

    char* ws = (char*)d_ws;
    float* Mpart = (float*)ws;                         // 8 KB
    float* Mbuf  = (float*)(ws + 8192);                // 1 KB
    u16* wqkv  = (u16*)(ws + 16384);                   // 1,572,864 B
    u16* wproj = (u16*)(ws + 16384 + 1572864);         // 524,288 B
    u16* wfc1  = (u16*)(ws + 16384 + 2097152);         // 2,097,152 B
    u16* wfc2  = (u16*)(ws + 16384 + 4194304);         // 2,097,152 B
    u16* bufA  = (u16*)(ws + 6307840);                 // 16.78 MB: img, then x1 (bf16)
    u16* bufB  = (u16*)(ws + 23085056);                // 16.78 MB: h1
    char* R    = ws + 39862272;                        // overlay region (67.1 MB)
    u16*   qkvb = (u16*)R;                             // 50,331,648 B
    u16*   Obuf = (u16*)(R + 50331648);                // 16,777,216 B
    u16*   gbuf = (u16*)R;                             // 67,108,864 B (qkv+O dead)

    // 0. all weight conversions f32->bf16 (one launch)
    cvt_all_k<<<3072, 256, 0, stream>>>(qkv_w, proj_w, fc1w, fc2w,
                                        wqkv, wproj, wfc1, wfc2);
    // 1. LN1: x -> img (bufA, bf16), wave-per-row
    ln_row_k<<<4096, 256, 0, stream>>>(x, n1w, n1b, bufA);
    // 2. qkv = img @ qkv_w^T  (qkvb bf16)
    gemm_bt<0, 0><<<dim3(128, 12), 256, 0, stream>>>(
        bufA, wqkv, nullptr, nullptr, nullptr, qkvb, 16384, 1536, 512,
        nullptr, nullptr, nullptr);
    // 3. fused attention: O' (no M factor) + Mpart
    attn_k<<<2048, 256, 0, stream>>>(qkvb, rpe, Mpart, Obuf);
    // 4. M finalize
    mfinal_k<<<1, 256, 0, stream>>>(Mpart, Mbuf);
    // 5. x1 = x + a1 @ proj_w^T + proj_b -> bufA (bf16); a1 fused in staging
    gemm_bt<1, 1><<<dim3(128, 4), 256, 0, stream>>>(
        Obuf, wproj, proj_b, x, nullptr, bufA, 16384, 512, 512,
        Mbuf, Obuf, x);
    // 6. LN2: x1 (bf16) -> h1 (bufB bf16), wave-per-row
    ln_row_bf_k<<<4096, 256, 0, stream>>>(bufA, n2w, n2b, bufB);
    // 7. g = gelu(h1 @ fc1_w^T + fc1_b)  (gbuf bf16)
    gemm_bt<2, 0><<<dim3(128, 16), 256, 0, stream>>>(
        bufB, wfc1, fc1b, nullptr, nullptr, gbuf, 16384, 2048, 512,
        nullptr, nullptr, nullptr);
    // 8. out = x1 + g @ fc2_w^T + fc2_b  (f32)
    gemm_bt<3, 0><<<dim3(128, 4), 256, 0, stream>>>(
        gbuf, wfc2, fc2b, nullptr, bufA, out, 16384, 512, 2048,
        nullptr, nullptr, nullptr);
}

// Round 13
// 186.912 us; speedup vs baseline: 1.1325x; 1.1325x over previous
//
#include <hip/hip_runtime.h>
#include <hip/hip_bf16.h>
#include <math.h>

typedef unsigned short u16;
typedef __bf16 bf16x8 __attribute__((ext_vector_type(8)));
typedef float f32x4 __attribute__((ext_vector_type(4)));
typedef unsigned short u16x8 __attribute__((ext_vector_type(8)));

typedef const __attribute__((address_space(1))) void* gas_ptr;
typedef __attribute__((address_space(3))) void* las_ptr;

__device__ __forceinline__ float bf2f(u16 u) {
    union { unsigned int i; float f; } x;
    x.i = ((unsigned int)u) << 16;
    return x.f;
}
__device__ __forceinline__ u16 f2bf(float f) {
    __hip_bfloat16 h = __float2bfloat16(f);
    return __builtin_bit_cast(u16, h);
}
__device__ __forceinline__ __bf16 f2bfr(float f) {
    __hip_bfloat16 h = __float2bfloat16(f);
    return __builtin_bit_cast(__bf16, h);
}
__device__ __forceinline__ void load_lds16(const void* g, void* l) {
    __builtin_amdgcn_global_load_lds((gas_ptr)g, (las_ptr)l, 16, 0, 0);
}
// GELU with exact-erf semantics via A&S 7.1.26 (|err_erf| <= 1.5e-7).
__device__ __forceinline__ float gelu_f(float v) {
    const float a = fabsf(v) * 0.70710678118654752f;
    const float tt = 1.0f / fmaf(0.3275911f, a, 1.0f);
    float poly = fmaf(tt, 1.061405429f, -1.453152027f);
    poly = fmaf(tt, poly, 1.421413741f);
    poly = fmaf(tt, poly, -0.284496736f);
    poly = fmaf(tt, poly, 0.254829592f);
    const float erfa = 1.0f - poly * tt * __expf(-a * a);
    const float erfv = copysignf(erfa, v);
    return 0.5f * v * (1.0f + erfv);
}

// ---------------------------------------------------------------------------
// All 4 weight conversions f32->bf16 in one launch. 1024 elems/block.
// ---------------------------------------------------------------------------
__global__ __launch_bounds__(256) void cvt_all_k(const float* __restrict__ qkv_w,
                                                 const float* __restrict__ proj_w,
                                                 const float* __restrict__ fc1w,
                                                 const float* __restrict__ fc2w,
                                                 u16* __restrict__ wqkv,
                                                 u16* __restrict__ wproj,
                                                 u16* __restrict__ wfc1,
                                                 u16* __restrict__ wfc2) {
    const int b = blockIdx.x;
    const float* src; u16* dst; int off;
    if (b < 768)       { src = qkv_w;  dst = wqkv;  off = b; }
    else if (b < 1024) { src = proj_w; dst = wproj; off = b - 768; }
    else if (b < 2048) { src = fc1w;   dst = wfc1;  off = b - 1024; }
    else               { src = fc2w;   dst = wfc2;  off = b - 2048; }
    const int i = off * 256 + threadIdx.x;
    const float4 v = ((const float4*)src)[i];
    ushort4 o;
    o.x = f2bf(v.x); o.y = f2bf(v.y); o.z = f2bf(v.z); o.w = f2bf(v.w);
    ((ushort4*)dst)[i] = o;
}

// ---------------------------------------------------------------------------
// LN1: one WAVE per row (C=512), 4 rows/block, no LDS/barrier. f32 -> bf16.
// ---------------------------------------------------------------------------
__global__ __launch_bounds__(256) void ln_row_k(const float* __restrict__ x,
                                                const float* __restrict__ gw,
                                                const float* __restrict__ gb,
                                                u16* __restrict__ outp) {
    const int row = blockIdx.x * 4 + (threadIdx.x >> 6);
    const int lane = threadIdx.x & 63;
    const float* rp = x + (size_t)row * 512 + lane * 8;
    const float4 a = *(const float4*)rp;
    const float4 b = *(const float4*)(rp + 4);
    float s = a.x + a.y + a.z + a.w + b.x + b.y + b.z + b.w;
    float q = a.x*a.x + a.y*a.y + a.z*a.z + a.w*a.w
            + b.x*b.x + b.y*b.y + b.z*b.z + b.w*b.w;
    #pragma unroll
    for (int o = 1; o < 64; o <<= 1) {
        s += __shfl_xor(s, o);
        q += __shfl_xor(q, o);
    }
    const float mean = s * (1.0f / 512.0f);
    const float var = q * (1.0f / 512.0f) - mean * mean;
    const float rstd = rsqrtf(var + 1e-5f);
    const float4 g0 = *(const float4*)(gw + lane * 8);
    const float4 g1 = *(const float4*)(gw + lane * 8 + 4);
    const float4 c0 = *(const float4*)(gb + lane * 8);
    const float4 c1 = *(const float4*)(gb + lane * 8 + 4);
    u16x8 o16;
    o16[0] = f2bf((a.x - mean) * rstd * g0.x + c0.x);
    o16[1] = f2bf((a.y - mean) * rstd * g0.y + c0.y);
    o16[2] = f2bf((a.z - mean) * rstd * g0.z + c0.z);
    o16[3] = f2bf((a.w - mean) * rstd * g0.w + c0.w);
    o16[4] = f2bf((b.x - mean) * rstd * g1.x + c1.x);
    o16[5] = f2bf((b.y - mean) * rstd * g1.y + c1.y);
    o16[6] = f2bf((b.z - mean) * rstd * g1.z + c1.z);
    o16[7] = f2bf((b.w - mean) * rstd * g1.w + c1.w);
    *(u16x8*)(outp + (size_t)row * 512 + lane * 8) = o16;
}

// ---------------------------------------------------------------------------
// LN2: one WAVE per row, bf16 in -> bf16 out, in-wave stats, no barrier.
// ---------------------------------------------------------------------------
__global__ __launch_bounds__(256) void ln_row_bf_k(const u16* __restrict__ x1,
                                                   const float* __restrict__ gw,
                                                   const float* __restrict__ gb,
                                                   u16* __restrict__ outp) {
    const int row = blockIdx.x * 4 + (threadIdx.x >> 6);
    const int lane = threadIdx.x & 63;
    const u16x8 v = *(const u16x8*)(x1 + (size_t)row * 512 + lane * 8);
    float f[8];
    float s = 0.f, q = 0.f;
    #pragma unroll
    for (int e = 0; e < 8; ++e) {
        f[e] = bf2f(v[e]);
        s += f[e]; q += f[e] * f[e];
    }
    #pragma unroll
    for (int o = 1; o < 64; o <<= 1) {
        s += __shfl_xor(s, o);
        q += __shfl_xor(q, o);
    }
    const float mean = s * (1.0f / 512.0f);
    const float var = q * (1.0f / 512.0f) - mean * mean;
    const float rstd = rsqrtf(var + 1e-5f);
    const float4 g0 = *(const float4*)(gw + lane * 8);
    const float4 g1 = *(const float4*)(gw + lane * 8 + 4);
    const float4 c0 = *(const float4*)(gb + lane * 8);
    const float4 c1 = *(const float4*)(gb + lane * 8 + 4);
    u16x8 o16;
    o16[0] = f2bf((f[0] - mean) * rstd * g0.x + c0.x);
    o16[1] = f2bf((f[1] - mean) * rstd * g0.y + c0.y);
    o16[2] = f2bf((f[2] - mean) * rstd * g0.z + c0.z);
    o16[3] = f2bf((f[3] - mean) * rstd * g0.w + c0.w);
    o16[4] = f2bf((f[4] - mean) * rstd * g1.x + c1.x);
    o16[5] = f2bf((f[5] - mean) * rstd * g1.y + c1.y);
    o16[6] = f2bf((f[6] - mean) * rstd * g1.z + c1.z);
    o16[7] = f2bf((f[7] - mean) * rstd * g1.w + c1.w);
    *(u16x8*)(outp + (size_t)row * 512 + lane * 8) = o16;
}

// ---------------------------------------------------------------------------
// GEMM C[m,n] = sum_k A[m,k]*W[n,k] (+epilogue). 128x128 tile, BK=64,
// 4 waves (2x2), each wave 64x64 via 4x4 mfma 16x16x32 (x2 K-halves).
// r8-exact core (measured best: fc1 65.7us): 2-buffer LDS (64 KB), one
// __syncthreads per 64-wide K-tile, swizzle slot = granule ^ (row&7) on both
// stage-source and frag-read (0 bank conflicts measured), A/B interleaved.
// AFUSE: A-tile computed on the fly as a1 = M*O' + (1-M)*x (reg-staged
//        ds_write into the same swizzled LDS slots).
// EPI 0: bf16 = acc (qkv); EPI 1: bf16 = acc+bias+res_f (proj -> x1 bf16);
// EPI 2: bf16 = gelu(acc+bias) (fc1); EPI 3: f32 = acc+bias+bf16res (fc2).
// ---------------------------------------------------------------------------
template<int EPI, bool AFUSE>
__global__ __launch_bounds__(256) void gemm_bt(const u16* __restrict__ A,
                                               const u16* __restrict__ W,
                                               const float* __restrict__ bias,
                                               const float* __restrict__ res_f,
                                               const u16* __restrict__ res_bf,
                                               void* __restrict__ outp,
                                               int M, int N, int K,
                                               const float* __restrict__ aM,
                                               const u16* __restrict__ aO,
                                               const float* __restrict__ aX) {
    __shared__ __bf16 As[2][128 * 64];
    __shared__ __bf16 Bs[2][128 * 64];
    const int t = threadIdx.x;
    const int l = t & 63;
    const int w = t >> 6;
    const int wm = w & 1, wn = w >> 1;
    const int bm = blockIdx.x * 128, bn = blockIdx.y * 128;
    const int r = l & 15, g4 = l >> 4;

    f32x4 acc[4][4] = {};

    // staging geometry: 1024 granules/tile; thread t handles granules
    // {t, t+256, t+512, t+768} -> rows rowS+32j, within-row slot t&7.
    const int rowS = t >> 3;
    const int cS = (t & 7) ^ (rowS & 7);        // data granule for this slot
    const size_t rstep = (size_t)32 * K;        // 32 rows
    const u16* wBase = W + (size_t)(bn + rowS) * K + cS * 8;
    const u16* aBase = AFUSE ? nullptr : (A + (size_t)(bm + rowS) * K + cS * 8);
    const size_t afBase = (size_t)(bm + rowS) * K + cS * 8;   // AFUSE index

    auto stage = [&](int buf, int kt) {
        #pragma unroll
        for (int j = 0; j < 4; ++j) {
            if (AFUSE) {
                const size_t gidx = afBase + j * rstep + kt;
                const float Mw = aM[(bm + rowS + j * 32) >> 6];
                const float rf = 1.0f - Mw;
                const u16x8 ov = *(const u16x8*)(aO + gidx);
                const float4 x0 = *(const float4*)(aX + gidx);
                const float4 x1 = *(const float4*)(aX + gidx + 4);
                bf16x8 val;
                val[0] = f2bfr(Mw * bf2f(ov[0]) + rf * x0.x);
                val[1] = f2bfr(Mw * bf2f(ov[1]) + rf * x0.y);
                val[2] = f2bfr(Mw * bf2f(ov[2]) + rf * x0.z);
                val[3] = f2bfr(Mw * bf2f(ov[3]) + rf * x0.w);
                val[4] = f2bfr(Mw * bf2f(ov[4]) + rf * x1.x);
                val[5] = f2bfr(Mw * bf2f(ov[5]) + rf * x1.y);
                val[6] = f2bfr(Mw * bf2f(ov[6]) + rf * x1.z);
                val[7] = f2bfr(Mw * bf2f(ov[7]) + rf * x1.w);
                *(bf16x8*)&As[buf][(j * 256 + t) * 8] = val;
            } else {
                load_lds16(aBase + j * rstep + kt, &As[buf][(j * 256 + t) * 8]);
            }
            load_lds16(wBase + j * rstep + kt, &Bs[buf][(j * 256 + t) * 8]);
        }
    };

    const int nk = K >> 6;
    stage(0, 0);
    __syncthreads();
    for (int s = 0; s < nk; ++s) {
        if (s + 1 < nk) stage((s + 1) & 1, (s + 1) << 6);
        const int buf = s & 1;
        bf16x8 af[4][2], bfr[4][2];
        #pragma unroll
        for (int i = 0; i < 4; ++i) {
            const int ra = wm * 64 + i * 16 + r;
            const int rb = wn * 64 + i * 16 + r;
            #pragma unroll
            for (int h = 0; h < 2; ++h) {
                af[i][h]  = *(const bf16x8*)&As[buf][ra * 64 + (((h * 4 + g4) ^ (ra & 7)) << 3)];
                bfr[i][h] = *(const bf16x8*)&Bs[buf][rb * 64 + (((h * 4 + g4) ^ (rb & 7)) << 3)];
            }
        }
        #pragma unroll
        for (int i = 0; i < 4; ++i)
            #pragma unroll
            for (int j = 0; j < 4; ++j)
                #pragma unroll
                for (int h = 0; h < 2; ++h)
                    acc[i][j] = __builtin_amdgcn_mfma_f32_16x16x32_bf16(
                        af[i][h], bfr[j][h], acc[i][j], 0, 0, 0);
        __syncthreads();
    }

    #pragma unroll
    for (int i = 0; i < 4; ++i) {
        #pragma unroll
        for (int j = 0; j < 4; ++j) {
            #pragma unroll
            for (int rr = 0; rr < 4; ++rr) {
                const int m = bm + wm * 64 + i * 16 + g4 * 4 + rr;
                const int n = bn + wn * 64 + j * 16 + r;
                float v = acc[i][j][rr];
                const size_t idx = (size_t)m * N + n;
                if (EPI == 0) {
                    ((u16*)outp)[idx] = f2bf(v);
                } else if (EPI == 1) {
                    ((u16*)outp)[idx] = f2bf(v + bias[n] + res_f[idx]);
                } else if (EPI == 2) {
                    ((u16*)outp)[idx] = f2bf(gelu_f(v + bias[n]));
                } else {
                    ((float*)outp)[idx] = v + bias[n] + bf2f(res_bf[idx]);
                }
            }
        }
    }
}

// ---------------------------------------------------------------------------
// Fused attention per (window, head): S = QK^T + 0.1*rpe ; Mpart = sum|S| ;
// P' = 1 - cos(S/||S||row * pi/2) ; O' = P' @ V  (M factor applied later).
// ---------------------------------------------------------------------------
__global__ __launch_bounds__(256) void attn_k(const u16* __restrict__ qkv,
                                              const float* __restrict__ rpe,
                                              float* __restrict__ Mpart,
                                              u16* __restrict__ Obuf) {
    const int blk = blockIdx.x;
    const int wh = blk >> 3, head = blk & 7;
    const int himg = wh & 63;
    const int t = threadIdx.x, l = t & 63, w = t >> 6;
    __shared__ __bf16 Qs[4096];
    __shared__ __bf16 Ks[4096];
    __shared__ __bf16 Vt[4096];
    __shared__ __bf16 Ps[4096];
    __shared__ float red[4];

    #pragma unroll
    for (int p = 0; p < 2; ++p) {
        const int sb = (p * 256 + t) << 4;
        const int row = sb >> 7;
        const int gl = ((sb >> 4) & 7) ^ (row & 7);
        const size_t gsrc = (size_t)(wh * 64 + row) * 1536 + head * 64 + gl * 8;
        const int lbase = p * 2048 + w * 512;
        load_lds16(qkv + gsrc, &Qs[lbase]);
        load_lds16(qkv + gsrc + 512, &Ks[lbase]);
    }
    {
        const int k = t >> 2, dc = (t & 3) * 16;
        const u16* vr = qkv + (size_t)(wh * 64 + k) * 1536 + 1024 + head * 64 + dc;
        u16x8 v0 = *(const u16x8*)vr;
        u16x8 v1 = *(const u16x8*)(vr + 8);
        const int g = k >> 3, klo = k & 7;
        #pragma unroll
        for (int i = 0; i < 8; ++i) {
            const int d0 = dc + i, d1 = dc + 8 + i;
            Vt[d0 * 64 + ((g ^ (d0 & 7)) << 3) + klo] = __builtin_bit_cast(__bf16, (u16)v0[i]);
            Vt[d1 * 64 + ((g ^ (d1 & 7)) << 3) + klo] = __builtin_bit_cast(__bf16, (u16)v1[i]);
        }
    }
    __syncthreads();

    const int r = l & 15, g4 = l >> 4;
    f32x4 acc[4] = {};
    #pragma unroll
    for (int h = 0; h < 2; ++h) {
        const int rowq = w * 16 + r;
        bf16x8 aq = *(const bf16x8*)&Qs[rowq * 64 + (((h * 4 + g4) ^ (rowq & 7)) << 3)];
        #pragma unroll
        for (int j = 0; j < 4; ++j) {
            const int rowk = j * 16 + r;
            bf16x8 bk = *(const bf16x8*)&Ks[rowk * 64 + (((h * 4 + g4) ^ (rowk & 7)) << 3)];
            acc[j] = __builtin_amdgcn_mfma_f32_16x16x32_bf16(aq, bk, acc[j], 0, 0, 0);
        }
    }

    float v[4][4];
    float asum = 0.f;
    float ss[4] = {0.f, 0.f, 0.f, 0.f};
    const size_t rpe_base = (size_t)(himg * 8 + head) * 4096 + (size_t)(w * 16 + g4 * 4) * 64 + r;
    #pragma unroll
    for (int j = 0; j < 4; ++j) {
        #pragma unroll
        for (int rr = 0; rr < 4; ++rr) {
            const float val = acc[j][rr] + 0.1f * rpe[rpe_base + rr * 64 + j * 16];
            v[j][rr] = val;
            asum += fabsf(val);
            ss[rr] += val * val;
        }
    }
    #pragma unroll
    for (int m = 1; m < 16; m <<= 1) {
        #pragma unroll
        for (int rr = 0; rr < 4; ++rr) ss[rr] += __shfl_xor(ss[rr], m);
    }
    float srev[4];
    #pragma unroll
    for (int rr = 0; rr < 4; ++rr)
        srev[rr] = 0.25f / fmaxf(sqrtf(ss[rr]), 1e-12f);

    #pragma unroll
    for (int j = 0; j < 4; ++j) {
        #pragma unroll
        for (int rr = 0; rr < 4; ++rr) {
            const float pv = 1.0f - __builtin_amdgcn_cosf(v[j][rr] * srev[rr]);
            const int rl = g4 * 4 + rr;
            const int c = j * 16 + r;
            Ps[w * 1024 + rl * 64 + (((c >> 3) ^ (rl & 7)) << 3) + (c & 7)] = f2bfr(pv);
        }
    }

    f32x4 oacc[4] = {};
    #pragma unroll
    for (int ks = 0; ks < 2; ++ks) {
        const int ga = ks * 4 + g4;
        bf16x8 pa = *(const bf16x8*)&Ps[w * 1024 + r * 64 + ((ga ^ (r & 7)) << 3)];
        #pragma unroll
        for (int j = 0; j < 4; ++j) {
            const int d = j * 16 + r;
            bf16x8 vb = *(const bf16x8*)&Vt[d * 64 + ((ga ^ (d & 7)) << 3)];
            oacc[j] = __builtin_amdgcn_mfma_f32_16x16x32_bf16(pa, vb, oacc[j], 0, 0, 0);
        }
    }

    #pragma unroll
    for (int j = 0; j < 4; ++j) {
        #pragma unroll
        for (int rr = 0; rr < 4; ++rr) {
            const int token = wh * 64 + w * 16 + g4 * 4 + rr;
            Obuf[(size_t)token * 512 + head * 64 + j * 16 + r] = f2bf(oacc[j][rr]);
        }
    }

    #pragma unroll
    for (int o = 1; o < 64; o <<= 1) asum += __shfl_xor(asum, o);
    if (l == 0) red[w] = asum;
    __syncthreads();
    if (t == 0) Mpart[blk] = red[0] + red[1] + red[2] + red[3];
}

// ---------------------------------------------------------------------------
// M finalize: M_w = mean|S| per window; M = max(M_w / max_w, 0.5). 1 block.
// ---------------------------------------------------------------------------
__global__ __launch_bounds__(256) void mfinal_k(const float* __restrict__ Mpart,
                                                float* __restrict__ M) {
    const int t = threadIdx.x;
    float m = 0.f;
    #pragma unroll
    for (int h = 0; h < 8; ++h) m += Mpart[t * 8 + h];
    m *= (1.0f / 32768.0f);
    float mx = m;
    #pragma unroll
    for (int o = 1; o < 64; o <<= 1) mx = fmaxf(mx, __shfl_xor(mx, o));
    __shared__ float red[4];
    if ((t & 63) == 0) red[t >> 6] = mx;
    __syncthreads();
    mx = fmaxf(fmaxf(red[0], red[1]), fmaxf(red[2], red[3]));
    M[t] = fmaxf(m / mx, 0.5f);
}

// ---------------------------------------------------------------------------
extern "C" void kernel_launch(void* const* d_in, const int* in_sizes, int n_in,
                              void* d_out, int out_size, void* d_ws, size_t ws_size,
                              hipStream_t stream) {
    (void)in_sizes; (void)n_in; (void)out_size; (void)ws_size;
    const float* x      = (const float*)d_in[0];
    const float* rpe    = (const float*)d_in[1];
    const float* qkv_w  = (const float*)d_in[2];
    const float* proj_w = (const float*)d_in[3];
    const float* proj_b = (const float*)d_in[4];
    const float* n1w    = (const float*)d_in[5];
    const float* n1b    = (const float*)d_in[6];
    const float* n2w    = (const float*)d_in[7];
    const float* n2b    = (const float*)d_in[8];
    const float* fc1w   = (const float*)d_in[9];
    const float* fc1b   = (const float*)d_in[10];
    const float* fc2w   = (const float*)d_in[11];
    const float* fc2b   = (const float*)d_in[12];
    float* out = (float*)d_out;

    char* ws = (char*)d_ws;
    float* Mpart = (float*)ws;                         // 8 KB
    float* Mbuf  = (float*)(ws + 8192);                // 1 KB
    u16* wqkv  = (u16*)(ws + 16384);                   // 1,572,864 B
    u16* wproj = (u16*)(ws + 16384 + 1572864);         // 524,288 B
    u16* wfc1  = (u16*)(ws + 16384 + 2097152);         // 2,097,152 B
    u16* wfc2  = (u16*)(ws + 16384 + 4194304);         // 2,097,152 B
    u16* bufA  = (u16*)(ws + 6307840);                 // 16.78 MB: img, then x1 (bf16)
    u16* bufB  = (u16*)(ws + 23085056);                // 16.78 MB: h1
    char* R    = ws + 39862272;                        // overlay region (67.1 MB)
    u16*   qkvb = (u16*)R;                             // 50,331,648 B
    u16*   Obuf = (u16*)(R + 50331648);                // 16,777,216 B
    u16*   gbuf = (u16*)R;                             // 67,108,864 B (qkv+O dead)

    // 0. all weight conversions f32->bf16 (one launch)
    cvt_all_k<<<3072, 256, 0, stream>>>(qkv_w, proj_w, fc1w, fc2w,
                                        wqkv, wproj, wfc1, wfc2);
    // 1. LN1: x -> img (bufA, bf16), wave-per-row
    ln_row_k<<<4096, 256, 0, stream>>>(x, n1w, n1b, bufA);
    // 2. qkv = img @ qkv_w^T  (qkvb bf16)
    gemm_bt<0, false><<<dim3(128, 12), 256, 0, stream>>>(
        bufA, wqkv, nullptr, nullptr, nullptr, qkvb, 16384, 1536, 512,
        nullptr, nullptr, nullptr);
    // 3. fused attention: O' (no M factor) + Mpart
    attn_k<<<2048, 256, 0, stream>>>(qkvb, rpe, Mpart, Obuf);
    // 4. M finalize
    mfinal_k<<<1, 256, 0, stream>>>(Mpart, Mbuf);
    // 5. x1 = x + a1 @ proj_w^T + proj_b -> bufA (bf16); a1 fused in staging
    gemm_bt<1, true><<<dim3(128, 4), 256, 0, stream>>>(
        nullptr, wproj, proj_b, x, nullptr, bufA, 16384, 512, 512,
        Mbuf, Obuf, x);
    // 6. LN2: x1 (bf16) -> h1 (bufB bf16), wave-per-row
    ln_row_bf_k<<<4096, 256, 0, stream>>>(bufA, n2w, n2b, bufB);
    // 7. g = gelu(h1 @ fc1_w^T + fc1_b)  (gbuf bf16)
    gemm_bt<2, false><<<dim3(128, 16), 256, 0, stream>>>(
        bufB, wfc1, fc1b, nullptr, nullptr, gbuf, 16384, 2048, 512,
        nullptr, nullptr, nullptr);
    // 8. out = x1 + g @ fc2_w^T + fc2_b  (f32)
    gemm_bt<3, false><<<dim3(128, 4), 256, 0, stream>>>(
        gbuf, wfc2, fc2b, nullptr, bufA, out, 16384, 512, 2048,
        nullptr, nullptr, nullptr);
}